// Round 1
// baseline (1123.024 us; speedup 1.0000x reference)
//
#include <hip/hip_runtime.h>
#include <hip/hip_bf16.h>

#define T_SEQ 2048
#define C_DIM 2048
#define L_DIM 512
#define H_NUM 16
#define S_DIM 128
#define B_SZ  2

typedef __attribute__((ext_vector_type(8))) short bf16x8;
typedef __attribute__((ext_vector_type(4))) float f32x4;
typedef __attribute__((ext_vector_type(4))) short short4v;

__device__ inline short f2bf(float f) {
    union { float f; unsigned u; } x; x.f = f;
    unsigned r = x.u + 0x7fffu + ((x.u >> 16) & 1u);
    return (short)(r >> 16);
}

// ---------------- cast fp32 -> bf16 (vectorized x4) ----------------
__global__ __launch_bounds__(256) void cast_bf16_kernel(const float* __restrict__ in,
                                                        short* __restrict__ out, int n4) {
    int i = blockIdx.x * 256 + threadIdx.x;
    if (i >= n4) return;
    float4 v = ((const float4*)in)[i];
    short4v o;
    o[0] = f2bf(v.x); o[1] = f2bf(v.y); o[2] = f2bf(v.z); o[3] = f2bf(v.w);
    ((short4v*)out)[i] = o;
}

// ------------- transpose + cast: in fp32 [R][C] -> out bf16 [C][R] -------------
__global__ __launch_bounds__(256) void tcast_kernel(const float* __restrict__ in,
                                                    short* __restrict__ out, int R, int C) {
    int c = blockIdx.x * 32 + (threadIdx.x & 31);
    int r = blockIdx.y * 8 + (threadIdx.x >> 5);
    out[(long)c * R + r] = f2bf(in[(long)r * C + c]);
}

// ------------- v [B*T][C] (bf16, viewed [B][T][H][S]) -> vt [B][H][S][T] -------------
__global__ __launch_bounds__(256) void vtrans_kernel(const short* __restrict__ v,
                                                     short* __restrict__ vt) {
    long idx = (long)blockIdx.x * 256 + threadIdx.x;   // over B*H*S*T = 8388608
    int t = (int)(idx & (T_SEQ - 1));
    long r = idx >> 11;
    int s = (int)(r & (S_DIM - 1)); r >>= 7;
    int h = (int)(r & (H_NUM - 1));
    int b = (int)(r >> 4);
    vt[idx] = v[((long)(b * T_SEQ + t)) * C_DIM + h * S_DIM + s];
}

// ------------- generic GEMM: C[M][N] = A[M][K] * Bt[N][K]^T  (bf16 in, fp32 acc) -------------
// 128x128 tile, BK=32, 256 threads = 4 waves (2x2), each wave 64x64 (4x4 mfma tiles)
template<int OUTF32>
__global__ __launch_bounds__(256) void gemm_bt_kernel(
    const short* __restrict__ A, const short* __restrict__ Bt,
    float* __restrict__ Cf, short* __restrict__ Cb,
    int M, int N, int K, int lda, int ldb, int ldc,
    long sAz, long sBz, long sCz)
{
    __shared__ __align__(16) short As[128 * 32];
    __shared__ __align__(16) short Bs[128 * 32];
    int z = blockIdx.z;
    A += (long)z * sAz;
    Bt += (long)z * sBz;
    long coff = (long)z * sCz;
    int tid = threadIdx.x;
    int m0 = blockIdx.y * 128, n0 = blockIdx.x * 128;
    int wave = tid >> 6, l = tid & 63;
    int wm = (wave >> 1) * 64, wn = (wave & 1) * 64;
    int lr = l & 15, lhi = l >> 4;
    f32x4 acc[4][4] = {};

    for (int k0 = 0; k0 < K; k0 += 32) {
        __syncthreads();
        #pragma unroll
        for (int r = 0; r < 2; r++) {
            int e = (r * 256 + tid) * 8;
            int row = e >> 5, col = e & 31;
            __builtin_amdgcn_global_load_lds(
                (const __attribute__((address_space(1))) unsigned int*)(A + (long)(m0 + row) * lda + k0 + col),
                (__attribute__((address_space(3))) unsigned int*)(&As[e]), 16, 0, 0);
            __builtin_amdgcn_global_load_lds(
                (const __attribute__((address_space(1))) unsigned int*)(Bt + (long)(n0 + row) * ldb + k0 + col),
                (__attribute__((address_space(3))) unsigned int*)(&Bs[e]), 16, 0, 0);
        }
        __syncthreads();
        bf16x8 af[4], bfr[4];
        #pragma unroll
        for (int mt = 0; mt < 4; mt++)
            af[mt] = *(const bf16x8*)&As[(wm + mt * 16 + lr) * 32 + lhi * 8];
        #pragma unroll
        for (int nt = 0; nt < 4; nt++)
            bfr[nt] = *(const bf16x8*)&Bs[(wn + nt * 16 + lr) * 32 + lhi * 8];
        #pragma unroll
        for (int mt = 0; mt < 4; mt++)
            #pragma unroll
            for (int nt = 0; nt < 4; nt++)
                acc[mt][nt] = __builtin_amdgcn_mfma_f32_16x16x32_bf16(af[mt], bfr[nt], acc[mt][nt], 0, 0, 0);
    }

    #pragma unroll
    for (int mt = 0; mt < 4; mt++) {
        #pragma unroll
        for (int i = 0; i < 4; i++) {
            int row = m0 + wm + mt * 16 + lhi * 4 + i;
            long base = coff + (long)row * ldc + n0 + wn;
            #pragma unroll
            for (int nt = 0; nt < 4; nt++) {
                float val = acc[mt][nt][i];
                int colo = nt * 16 + lr;
                if (OUTF32) Cf[base + colo] = val;
                else        Cb[base + colo] = f2bf(val);
            }
        }
    }
}

// ------------- flash attention: one wave handles 16 q-rows for one (b,h) -------------
// scores = qlat[b,h] (T x L) @ kv[b]^T (L x T) * scale, causal, online softmax, y = P @ V
__global__ __launch_bounds__(64) void flash_kernel(
    const short* __restrict__ qlat,  // [H][B][T][L]
    const short* __restrict__ kv,    // [B][T][L]
    const short* __restrict__ vt,    // [B][H][S][T]
    short* __restrict__ y)           // [B][T][C] (C = H*S)
{
    int t0 = blockIdx.x * 16;
    int h = blockIdx.y, b = blockIdx.z;
    int l = threadIdx.x, lr = l & 15, lhi = l >> 4;
    const short* qb  = qlat + ((long)(h * B_SZ + b)) * T_SEQ * L_DIM;
    const short* kvb = kv + (long)b * T_SEQ * L_DIM;
    const short* vtb = vt + ((long)(b * H_NUM + h)) * S_DIM * T_SEQ;

    bf16x8 qf[16];
    #pragma unroll
    for (int ks = 0; ks < 16; ks++)
        qf[ks] = *(const bf16x8*)&qb[(long)(t0 + lr) * L_DIM + ks * 32 + lhi * 8];

    f32x4 yacc[8] = {};
    float mrun[4], lrun[4];
    #pragma unroll
    for (int i = 0; i < 4; i++) { mrun[i] = -__builtin_inff(); lrun[i] = 0.f; }

    __shared__ __align__(16) short P[16 * 32];
    const float scale = 0.022097086912079608f;  // 1/sqrt(2048)

    int nchunk = (t0 + 16 + 31) >> 5;
    for (int c = 0; c < nchunk; c++) {
        int s0 = c * 32;
        f32x4 sc0 = {}, sc1 = {};
        #pragma unroll
        for (int ks = 0; ks < 16; ks++) {
            bf16x8 kf0 = *(const bf16x8*)&kvb[(long)(s0 + lr) * L_DIM + ks * 32 + lhi * 8];
            sc0 = __builtin_amdgcn_mfma_f32_16x16x32_bf16(qf[ks], kf0, sc0, 0, 0, 0);
        }
        #pragma unroll
        for (int ks = 0; ks < 16; ks++) {
            bf16x8 kf1 = *(const bf16x8*)&kvb[(long)(s0 + 16 + lr) * L_DIM + ks * 32 + lhi * 8];
            sc1 = __builtin_amdgcn_mfma_f32_16x16x32_bf16(qf[ks], kf1, sc1, 0, 0, 0);
        }
        float p0[4], p1[4], mx[4];
        #pragma unroll
        for (int i = 0; i < 4; i++) {
            int trow = t0 + lhi * 4 + i;
            float a0 = sc0[i] * scale, a1 = sc1[i] * scale;
            if (s0 + lr > trow)      a0 = -__builtin_inff();
            if (s0 + 16 + lr > trow) a1 = -__builtin_inff();
            p0[i] = a0; p1[i] = a1;
            mx[i] = fmaxf(a0, a1);
        }
        #pragma unroll
        for (int off = 1; off < 16; off <<= 1)
            #pragma unroll
            for (int i = 0; i < 4; i++)
                mx[i] = fmaxf(mx[i], __shfl_xor(mx[i], off, 16));
        float fac[4], ls[4];
        #pragma unroll
        for (int i = 0; i < 4; i++) {
            float mnew = fmaxf(mrun[i], mx[i]);
            fac[i] = __expf(mrun[i] - mnew);
            mrun[i] = mnew;
            p0[i] = __expf(p0[i] - mnew);
            p1[i] = __expf(p1[i] - mnew);
            ls[i] = p0[i] + p1[i];
        }
        #pragma unroll
        for (int off = 1; off < 16; off <<= 1)
            #pragma unroll
            for (int i = 0; i < 4; i++)
                ls[i] += __shfl_xor(ls[i], off, 16);
        #pragma unroll
        for (int i = 0; i < 4; i++) lrun[i] = lrun[i] * fac[i] + ls[i];
        #pragma unroll
        for (int st = 0; st < 8; st++)
            #pragma unroll
            for (int i = 0; i < 4; i++)
                yacc[st][i] *= fac[i];
        __syncthreads();
        #pragma unroll
        for (int i = 0; i < 4; i++) {
            P[(lhi * 4 + i) * 32 + lr]      = f2bf(p0[i]);
            P[(lhi * 4 + i) * 32 + 16 + lr] = f2bf(p1[i]);
        }
        __syncthreads();
        bf16x8 pf = *(const bf16x8*)&P[lr * 32 + lhi * 8];
        #pragma unroll
        for (int st = 0; st < 8; st++) {
            bf16x8 vf = *(const bf16x8*)&vtb[(long)(st * 16 + lr) * T_SEQ + s0 + lhi * 8];
            yacc[st] = __builtin_amdgcn_mfma_f32_16x16x32_bf16(pf, vf, yacc[st], 0, 0, 0);
        }
    }
    #pragma unroll
    for (int st = 0; st < 8; st++)
        #pragma unroll
        for (int i = 0; i < 4; i++) {
            int trow = t0 + lhi * 4 + i;
            float val = yacc[st][i] / lrun[i];
            y[((long)(b * T_SEQ + trow)) * C_DIM + h * S_DIM + st * 16 + lr] = f2bf(val);
        }
}

extern "C" void kernel_launch(void* const* d_in, const int* in_sizes, int n_in,
                              void* d_out, int out_size, void* d_ws, size_t ws_size,
                              hipStream_t stream) {
    const float* x    = (const float*)d_in[0];
    const float* wdkv = (const float*)d_in[1];
    const float* wuk  = (const float*)d_in[2];
    const float* wuv  = (const float*)d_in[3];
    const float* wq   = (const float*)d_in[4];
    const float* wo   = (const float*)d_in[5];
    float* out = (float*)d_out;

    short* ws = (short*)d_ws;
    size_t off = 0;
    short* xb    = ws + off; off += (size_t)4096 * 2048;   // x bf16 [B*T][C]   (reused as vt)
    short* wqT   = ws + off; off += (size_t)2048 * 2048;   // [C_out][C_in]
    short* wdkvT = ws + off; off += (size_t)512 * 2048;    // [L][C]
    short* wukT  = ws + off; off += (size_t)512 * 2048;    // [L][C]
    short* wuvT  = ws + off; off += (size_t)2048 * 512;    // [C][L]
    short* woT   = ws + off; off += (size_t)2048 * 2048;   // [C][C]
    short* q     = ws + off; off += (size_t)4096 * 2048;   // [B*T][C]         (reused as y)
    short* kvb   = ws + off; off += (size_t)4096 * 512;    // [B*T][L]
    short* vbuf  = ws + off; off += (size_t)4096 * 2048;   // [B*T][C]
    short* qlat  = ws + off; off += (size_t)H_NUM * B_SZ * T_SEQ * L_DIM; // [H][B][T][L]
    short* vtb  = xb;   // vt [B][H][S][T], aliases xb (dead by then)
    short* ybuf = q;    // y  [B][T][C],   aliases q  (dead by then)

    // casts / transposes
    cast_bf16_kernel<<<8192, 256, 0, stream>>>(x, xb, 2097152);
    tcast_kernel<<<dim3(2048 / 32, 2048 / 8), 256, 0, stream>>>(wq, wqT, 2048, 2048);
    tcast_kernel<<<dim3(512 / 32, 2048 / 8), 256, 0, stream>>>(wdkv, wdkvT, 2048, 512);
    tcast_kernel<<<dim3(512 / 32, 2048 / 8), 256, 0, stream>>>(wuk, wukT, 2048, 512);
    tcast_kernel<<<dim3(2048 / 32, 512 / 8), 256, 0, stream>>>(wuv, wuvT, 512, 2048);
    tcast_kernel<<<dim3(2048 / 32, 2048 / 8), 256, 0, stream>>>(wo, woT, 2048, 2048);

    // q = x @ w_q            [4096 x 2048] k=2048
    gemm_bt_kernel<0><<<dim3(16, 32, 1), 256, 0, stream>>>(xb, wqT, nullptr, q,
        4096, 2048, 2048, 2048, 2048, 2048, 0, 0, 0);
    // kv = x @ w_dkv         [4096 x 512] k=2048
    gemm_bt_kernel<0><<<dim3(4, 32, 1), 256, 0, stream>>>(xb, wdkvT, nullptr, kvb,
        4096, 512, 2048, 2048, 2048, 512, 0, 0, 0);
    // qlat[h] = q_h @ w_uk_h [4096 x 512] k=128, batched over 16 heads
    gemm_bt_kernel<0><<<dim3(4, 32, 16), 256, 0, stream>>>(q, wukT, nullptr, qlat,
        4096, 512, 128, 2048, 2048, 512, 128, 128, (long)B_SZ * T_SEQ * L_DIM);
    // v = kv @ w_uv          [4096 x 2048] k=512
    gemm_bt_kernel<0><<<dim3(16, 32, 1), 256, 0, stream>>>(kvb, wuvT, nullptr, vbuf,
        4096, 2048, 512, 512, 512, 2048, 0, 0, 0);
    // v transpose -> [B][H][S][T]
    vtrans_kernel<<<32768, 256, 0, stream>>>(vbuf, vtb);
    // flash attention -> y [B][T][C]
    flash_kernel<<<dim3(T_SEQ / 16, H_NUM, B_SZ), 64, 0, stream>>>(qlat, kvb, vtb, ybuf);
    // out = y @ w_o          [4096 x 2048] k=2048, fp32 out
    gemm_bt_kernel<1><<<dim3(16, 32, 1), 256, 0, stream>>>(ybuf, woT, out, nullptr,
        4096, 2048, 2048, 2048, 2048, 2048, 0, 0, 0);
}

// Round 2
// 666.363 us; speedup vs baseline: 1.6853x; 1.6853x over previous
//
#include <hip/hip_runtime.h>
#include <hip/hip_bf16.h>

#define T_SEQ 2048
#define C_DIM 2048
#define L_DIM 512
#define H_NUM 16
#define S_DIM 128
#define B_SZ  2

typedef __attribute__((ext_vector_type(8))) short bf16x8;
typedef __attribute__((ext_vector_type(4))) float f32x4;
typedef __attribute__((ext_vector_type(4))) short short4v;

__device__ inline short f2bf(float f) {
    union { float f; unsigned u; } x; x.f = f;
    unsigned r = x.u + 0x7fffu + ((x.u >> 16) & 1u);
    return (short)(r >> 16);
}

// ---------------- cast fp32 -> bf16 (vectorized x4) ----------------
__global__ __launch_bounds__(256) void cast_bf16_kernel(const float* __restrict__ in,
                                                        short* __restrict__ out, int n4) {
    int i = blockIdx.x * 256 + threadIdx.x;
    if (i >= n4) return;
    float4 v = ((const float4*)in)[i];
    short4v o;
    o[0] = f2bf(v.x); o[1] = f2bf(v.y); o[2] = f2bf(v.z); o[3] = f2bf(v.w);
    ((short4v*)out)[i] = o;
}

// ------------- transpose + cast: in fp32 [R][C] -> out bf16 [C][R] -------------
__global__ __launch_bounds__(256) void tcast_kernel(const float* __restrict__ in,
                                                    short* __restrict__ out, int R, int C) {
    int c = blockIdx.x * 32 + (threadIdx.x & 31);
    int r = blockIdx.y * 8 + (threadIdx.x >> 5);
    out[(long)c * R + r] = f2bf(in[(long)r * C + c]);
}

// ------------- v [B*T][C] (bf16, viewed [B][T][H][S]) -> vt [B][H][S][T] -------------
__global__ __launch_bounds__(256) void vtrans_kernel(const short* __restrict__ v,
                                                     short* __restrict__ vt) {
    long idx = (long)blockIdx.x * 256 + threadIdx.x;   // over B*H*S*T = 8388608
    int t = (int)(idx & (T_SEQ - 1));
    long r = idx >> 11;
    int s = (int)(r & (S_DIM - 1)); r >>= 7;
    int h = (int)(r & (H_NUM - 1));
    int b = (int)(r >> 4);
    vt[idx] = v[((long)(b * T_SEQ + t)) * C_DIM + h * S_DIM + s];
}

// ------------- generic GEMM: C[M][N] = A[M][K] * Bt[N][K]^T  (bf16 in, fp32 acc) -------------
template<int OUTF32>
__global__ __launch_bounds__(256) void gemm_bt_kernel(
    const short* __restrict__ A, const short* __restrict__ Bt,
    float* __restrict__ Cf, short* __restrict__ Cb,
    int M, int N, int K, int lda, int ldb, int ldc,
    long sAz, long sBz, long sCz)
{
    __shared__ __align__(16) short As[128 * 32];
    __shared__ __align__(16) short Bs[128 * 32];
    int z = blockIdx.z;
    A += (long)z * sAz;
    Bt += (long)z * sBz;
    long coff = (long)z * sCz;
    int tid = threadIdx.x;
    int m0 = blockIdx.y * 128, n0 = blockIdx.x * 128;
    int wave = tid >> 6, l = tid & 63;
    int wm = (wave >> 1) * 64, wn = (wave & 1) * 64;
    int lr = l & 15, lhi = l >> 4;
    f32x4 acc[4][4] = {};

    for (int k0 = 0; k0 < K; k0 += 32) {
        __syncthreads();
        #pragma unroll
        for (int r = 0; r < 2; r++) {
            int e = (r * 256 + tid) * 8;
            int row = e >> 5, col = e & 31;
            __builtin_amdgcn_global_load_lds(
                (const __attribute__((address_space(1))) unsigned int*)(A + (long)(m0 + row) * lda + k0 + col),
                (__attribute__((address_space(3))) unsigned int*)(&As[e]), 16, 0, 0);
            __builtin_amdgcn_global_load_lds(
                (const __attribute__((address_space(1))) unsigned int*)(Bt + (long)(n0 + row) * ldb + k0 + col),
                (__attribute__((address_space(3))) unsigned int*)(&Bs[e]), 16, 0, 0);
        }
        __syncthreads();
        bf16x8 af[4], bfr[4];
        #pragma unroll
        for (int mt = 0; mt < 4; mt++)
            af[mt] = *(const bf16x8*)&As[(wm + mt * 16 + lr) * 32 + lhi * 8];
        #pragma unroll
        for (int nt = 0; nt < 4; nt++)
            bfr[nt] = *(const bf16x8*)&Bs[(wn + nt * 16 + lr) * 32 + lhi * 8];
        #pragma unroll
        for (int mt = 0; mt < 4; mt++)
            #pragma unroll
            for (int nt = 0; nt < 4; nt++)
                acc[mt][nt] = __builtin_amdgcn_mfma_f32_16x16x32_bf16(af[mt], bfr[nt], acc[mt][nt], 0, 0, 0);
    }

    #pragma unroll
    for (int mt = 0; mt < 4; mt++) {
        #pragma unroll
        for (int i = 0; i < 4; i++) {
            int row = m0 + wm + mt * 16 + lhi * 4 + i;
            long base = coff + (long)row * ldc + n0 + wn;
            #pragma unroll
            for (int nt = 0; nt < 4; nt++) {
                float val = acc[mt][nt][i];
                int colo = nt * 16 + lr;
                if (OUTF32) Cf[base + colo] = val;
                else        Cb[base + colo] = f2bf(val);
            }
        }
    }
}

// ------------- flash attention v2: 4 waves/block, QBLK=64, KVBLK=32, LDS-staged K/V -------------
// K LDS rows are 1024B: read-swizzle byte ^= (row&7)<<4; V/P rows are 64B: byte ^= ((row>>1)&3)<<4.
// LDS dest of global_load_lds stays linear; the XOR is pre-applied to the global SOURCE (rule #21).
__global__ __launch_bounds__(256) void flash2_kernel(
    const short* __restrict__ qlat,  // [H][B][T][L]
    const short* __restrict__ kv,    // [B][T][L]
    const short* __restrict__ vt,    // [B][H][S][T]
    short* __restrict__ y)           // [B][T][C]
{
    __shared__ __align__(16) short Ks[32 * 512];   // 32 KB
    __shared__ __align__(16) short Vs[128 * 32];   // 8 KB
    __shared__ __align__(16) short Ps[4 * 16 * 32];// 4 KB (1KB per wave)

    int qt = gridDim.x - 1 - blockIdx.x;           // heaviest tiles first
    int t0 = qt * 64;
    int h = blockIdx.y, b = blockIdx.z;
    int tid = threadIdx.x;
    int w = tid >> 6, l = tid & 63, lr = l & 15, lhi = l >> 4;
    int wt0 = t0 + w * 16;                          // this wave's 16 q-rows
    const short* qb  = qlat + ((long)(h * B_SZ + b)) * T_SEQ * L_DIM;
    const short* kvb = kv + (long)b * T_SEQ * L_DIM;
    const short* vtb = vt + ((long)(b * H_NUM + h)) * S_DIM * T_SEQ;
    short* Pw = Ps + w * 512;

    bf16x8 qf[16];
    #pragma unroll
    for (int ks = 0; ks < 16; ks++)
        qf[ks] = *(const bf16x8*)&qb[(long)(wt0 + lr) * L_DIM + ks * 32 + lhi * 8];

    f32x4 yacc[8] = {};
    float mrun[4], lrun[4];
    #pragma unroll
    for (int i = 0; i < 4; i++) { mrun[i] = -__builtin_inff(); lrun[i] = 0.f; }
    const float scale = 0.022097086912079608f;  // 1/sqrt(2048)

    int nchunk = (t0 >> 5) + 2;
    for (int c = 0; c < nchunk; c++) {
        int s0 = c * 32;
        __syncthreads();   // everyone done reading Ks/Vs from prev chunk
        // ---- stage K chunk [32][512] (32KB), source pre-swizzled ----
        #pragma unroll
        for (int r = 0; r < 8; r++) {
            int flat = r * 4096 + tid * 16;
            int row = flat >> 10, colb = flat & 1023;
            int src = ((s0 + row) << 10) + (colb ^ ((row & 7) << 4));
            __builtin_amdgcn_global_load_lds(
                (const __attribute__((address_space(1))) unsigned int*)((const char*)kvb + src),
                (__attribute__((address_space(3))) unsigned int*)((char*)Ks + flat), 16, 0, 0);
        }
        // ---- stage V chunk [128][32] (8KB) from vt, source pre-swizzled ----
        #pragma unroll
        for (int r = 0; r < 2; r++) {
            int flat = r * 4096 + tid * 16;
            int row = flat >> 6, colb = flat & 63;
            long src = (long)row * (T_SEQ * 2) + (long)s0 * 2 + (colb ^ (((row >> 1) & 3) << 4));
            __builtin_amdgcn_global_load_lds(
                (const __attribute__((address_space(1))) unsigned int*)((const char*)vtb + src),
                (__attribute__((address_space(3))) unsigned int*)((char*)Vs + flat), 16, 0, 0);
        }
        __syncthreads();   // staging complete (vmcnt drained by barrier)

        bool active = (s0 < wt0 + 16);   // wave-uniform
        float p0[4], p1[4];
        if (active) {
            // ---- QK^T: two 16-col tiles, each as 2 independent 8-MFMA chains ----
            f32x4 sc[2];
            #pragma unroll
            for (int ct = 0; ct < 2; ct++) {
                int row = ct * 16 + lr;
                int swz = (row & 7) << 4;
                const char* kbase = (const char*)Ks + (row << 10);
                f32x4 sA = {}, sB = {};
                #pragma unroll
                for (int ks = 0; ks < 8; ks++) {
                    bf16x8 kfA = *(const bf16x8*)(kbase + ((ks * 64 + lhi * 16) ^ swz));
                    bf16x8 kfB = *(const bf16x8*)(kbase + (((ks + 8) * 64 + lhi * 16) ^ swz));
                    sA = __builtin_amdgcn_mfma_f32_16x16x32_bf16(qf[ks], kfA, sA, 0, 0, 0);
                    sB = __builtin_amdgcn_mfma_f32_16x16x32_bf16(qf[ks + 8], kfB, sB, 0, 0, 0);
                }
                sc[ct] = sA + sB;
            }
            // ---- online softmax over the 32 cols (rows = wt0 + lhi*4+i) ----
            float mx[4];
            #pragma unroll
            for (int i = 0; i < 4; i++) {
                int trow = wt0 + lhi * 4 + i;
                float a0 = sc[0][i] * scale, a1 = sc[1][i] * scale;
                if (s0 + lr > trow)      a0 = -__builtin_inff();
                if (s0 + 16 + lr > trow) a1 = -__builtin_inff();
                p0[i] = a0; p1[i] = a1;
                mx[i] = fmaxf(a0, a1);
            }
            #pragma unroll
            for (int off = 1; off < 16; off <<= 1)
                #pragma unroll
                for (int i = 0; i < 4; i++)
                    mx[i] = fmaxf(mx[i], __shfl_xor(mx[i], off, 16));
            float fac[4], lsum[4];
            #pragma unroll
            for (int i = 0; i < 4; i++) {
                float mnew = fmaxf(mrun[i], mx[i]);
                fac[i] = __expf(mrun[i] - mnew);
                mrun[i] = mnew;
                p0[i] = __expf(p0[i] - mnew);
                p1[i] = __expf(p1[i] - mnew);
                lsum[i] = p0[i] + p1[i];
            }
            #pragma unroll
            for (int off = 1; off < 16; off <<= 1)
                #pragma unroll
                for (int i = 0; i < 4; i++)
                    lsum[i] += __shfl_xor(lsum[i], off, 16);
            #pragma unroll
            for (int i = 0; i < 4; i++) lrun[i] = lrun[i] * fac[i] + lsum[i];
            #pragma unroll
            for (int st = 0; st < 8; st++)
                #pragma unroll
                for (int i = 0; i < 4; i++)
                    yacc[st][i] *= fac[i];
            // ---- write P to per-wave LDS (swizzled rows of 64B) ----
            #pragma unroll
            for (int i = 0; i < 4; i++) {
                int row = lhi * 4 + i;
                int swz = ((row >> 1) & 3) << 4;
                char* pb = (char*)Pw + row * 64;
                *(short*)(pb + ((lr * 2) ^ swz))        = f2bf(p0[i]);
                *(short*)(pb + (((16 + lr) * 2) ^ swz)) = f2bf(p1[i]);
            }
        }
        __syncthreads();   // P visible (cross-lane), Ks/Vs still valid
        if (active) {
            int swp = ((lr >> 1) & 3) << 4;
            bf16x8 pf = *(const bf16x8*)((const char*)Pw + lr * 64 + ((lhi * 16) ^ swp));
            #pragma unroll
            for (int st = 0; st < 8; st++) {
                int vrow = st * 16 + lr;
                bf16x8 vf = *(const bf16x8*)((const char*)Vs + vrow * 64 + ((lhi * 16) ^ (((vrow >> 1) & 3) << 4)));
                yacc[st] = __builtin_amdgcn_mfma_f32_16x16x32_bf16(pf, vf, yacc[st], 0, 0, 0);
            }
        }
    }

    #pragma unroll
    for (int st = 0; st < 8; st++)
        #pragma unroll
        for (int i = 0; i < 4; i++) {
            int trow = wt0 + lhi * 4 + i;
            float val = yacc[st][i] / lrun[i];
            y[((long)(b * T_SEQ + trow)) * C_DIM + h * S_DIM + st * 16 + lr] = f2bf(val);
        }
}

extern "C" void kernel_launch(void* const* d_in, const int* in_sizes, int n_in,
                              void* d_out, int out_size, void* d_ws, size_t ws_size,
                              hipStream_t stream) {
    const float* x    = (const float*)d_in[0];
    const float* wdkv = (const float*)d_in[1];
    const float* wuk  = (const float*)d_in[2];
    const float* wuv  = (const float*)d_in[3];
    const float* wq   = (const float*)d_in[4];
    const float* wo   = (const float*)d_in[5];
    float* out = (float*)d_out;

    short* ws = (short*)d_ws;
    size_t off = 0;
    short* xb    = ws + off; off += (size_t)4096 * 2048;   // x bf16 [B*T][C]   (reused as vt)
    short* wqT   = ws + off; off += (size_t)2048 * 2048;   // [C_out][C_in]
    short* wdkvT = ws + off; off += (size_t)512 * 2048;    // [L][C]
    short* wukT  = ws + off; off += (size_t)512 * 2048;    // [L][C]
    short* wuvT  = ws + off; off += (size_t)2048 * 512;    // [C][L]
    short* woT   = ws + off; off += (size_t)2048 * 2048;   // [C][C]
    short* q     = ws + off; off += (size_t)4096 * 2048;   // [B*T][C]         (reused as y)
    short* kvb   = ws + off; off += (size_t)4096 * 512;    // [B*T][L]
    short* vbuf  = ws + off; off += (size_t)4096 * 2048;   // [B*T][C]
    short* qlat  = ws + off; off += (size_t)H_NUM * B_SZ * T_SEQ * L_DIM; // [H][B][T][L]
    short* vtb  = xb;   // vt [B][H][S][T], aliases xb (dead by then)
    short* ybuf = q;    // y  [B][T][C],   aliases q  (dead by then)

    // casts / transposes
    cast_bf16_kernel<<<8192, 256, 0, stream>>>(x, xb, 2097152);
    tcast_kernel<<<dim3(2048 / 32, 2048 / 8), 256, 0, stream>>>(wq, wqT, 2048, 2048);
    tcast_kernel<<<dim3(512 / 32, 2048 / 8), 256, 0, stream>>>(wdkv, wdkvT, 2048, 512);
    tcast_kernel<<<dim3(512 / 32, 2048 / 8), 256, 0, stream>>>(wuk, wukT, 2048, 512);
    tcast_kernel<<<dim3(2048 / 32, 512 / 8), 256, 0, stream>>>(wuv, wuvT, 512, 2048);
    tcast_kernel<<<dim3(2048 / 32, 2048 / 8), 256, 0, stream>>>(wo, woT, 2048, 2048);

    // q = x @ w_q            [4096 x 2048] k=2048
    gemm_bt_kernel<0><<<dim3(16, 32, 1), 256, 0, stream>>>(xb, wqT, nullptr, q,
        4096, 2048, 2048, 2048, 2048, 2048, 0, 0, 0);
    // kv = x @ w_dkv         [4096 x 512] k=2048
    gemm_bt_kernel<0><<<dim3(4, 32, 1), 256, 0, stream>>>(xb, wdkvT, nullptr, kvb,
        4096, 512, 2048, 2048, 2048, 512, 0, 0, 0);
    // qlat[h] = q_h @ w_uk_h [4096 x 512] k=128, batched over 16 heads
    gemm_bt_kernel<0><<<dim3(4, 32, 16), 256, 0, stream>>>(q, wukT, nullptr, qlat,
        4096, 512, 128, 2048, 2048, 512, 128, 128, (long)B_SZ * T_SEQ * L_DIM);
    // v = kv @ w_uv          [4096 x 2048] k=512
    gemm_bt_kernel<0><<<dim3(16, 32, 1), 256, 0, stream>>>(kvb, wuvT, nullptr, vbuf,
        4096, 2048, 512, 512, 512, 2048, 0, 0, 0);
    // v transpose -> [B][H][S][T]
    vtrans_kernel<<<32768, 256, 0, stream>>>(vbuf, vtb);
    // flash attention v2 -> y [B][T][C]
    flash2_kernel<<<dim3(T_SEQ / 64, H_NUM, B_SZ), 256, 0, stream>>>(qlat, kvb, vtb, ybuf);
    // out = y @ w_o          [4096 x 2048] k=2048, fp32 out
    gemm_bt_kernel<1><<<dim3(16, 32, 1), 256, 0, stream>>>(ybuf, woT, out, nullptr,
        4096, 2048, 2048, 2048, 2048, 2048, 0, 0, 0);
}

// Round 4
// 655.741 us; speedup vs baseline: 1.7126x; 1.0162x over previous
//
#include <hip/hip_runtime.h>
#include <hip/hip_bf16.h>

#define T_SEQ 2048
#define C_DIM 2048
#define L_DIM 512
#define H_NUM 16
#define S_DIM 128
#define B_SZ  2

typedef __attribute__((ext_vector_type(8))) short bf16x8;
typedef __attribute__((ext_vector_type(4))) float f32x4;
typedef __attribute__((ext_vector_type(4))) short short4v;

__device__ inline short f2bf(float f) {
    union { float f; unsigned u; } x; x.f = f;
    unsigned r = x.u + 0x7fffu + ((x.u >> 16) & 1u);
    return (short)(r >> 16);
}

// ---------------- cast fp32 -> bf16 (vectorized x4) ----------------
__global__ __launch_bounds__(256) void cast_bf16_kernel(const float* __restrict__ in,
                                                        short* __restrict__ out, int n4) {
    int i = blockIdx.x * 256 + threadIdx.x;
    if (i >= n4) return;
    float4 v = ((const float4*)in)[i];
    short4v o;
    o[0] = f2bf(v.x); o[1] = f2bf(v.y); o[2] = f2bf(v.z); o[3] = f2bf(v.w);
    ((short4v*)out)[i] = o;
}

// ------------- transpose + cast: in fp32 [R][C] -> out bf16 [C][R] -------------
__global__ __launch_bounds__(256) void tcast_kernel(const float* __restrict__ in,
                                                    short* __restrict__ out, int R, int C) {
    int c = blockIdx.x * 32 + (threadIdx.x & 31);
    int r = blockIdx.y * 8 + (threadIdx.x >> 5);
    out[(long)c * R + r] = f2bf(in[(long)r * C + c]);
}

// ------------- v [B*T][C] (bf16, viewed [B][T][H][S]) -> vt [B][H][S][T] -------------
__global__ __launch_bounds__(256) void vtrans_kernel(const short* __restrict__ v,
                                                     short* __restrict__ vt) {
    long idx = (long)blockIdx.x * 256 + threadIdx.x;   // over B*H*S*T = 8388608
    int t = (int)(idx & (T_SEQ - 1));
    long r = idx >> 11;
    int s = (int)(r & (S_DIM - 1)); r >>= 7;
    int h = (int)(r & (H_NUM - 1));
    int b = (int)(r >> 4);
    vt[idx] = v[((long)(b * T_SEQ + t)) * C_DIM + h * S_DIM + s];
}

// ------------- generic GEMM: C[M][N] = A[M][K] * Bt[N][K]^T  (bf16 in, fp32 acc) -------------
template<int OUTF32>
__global__ __launch_bounds__(256) void gemm_bt_kernel(
    const short* __restrict__ A, const short* __restrict__ Bt,
    float* __restrict__ Cf, short* __restrict__ Cb,
    int M, int N, int K, int lda, int ldb, int ldc,
    long sAz, long sBz, long sCz)
{
    __shared__ __align__(16) short As[128 * 32];
    __shared__ __align__(16) short Bs[128 * 32];
    int z = blockIdx.z;
    A += (long)z * sAz;
    Bt += (long)z * sBz;
    long coff = (long)z * sCz;
    int tid = threadIdx.x;
    int m0 = blockIdx.y * 128, n0 = blockIdx.x * 128;
    int wave = tid >> 6, l = tid & 63;
    int wm = (wave >> 1) * 64, wn = (wave & 1) * 64;
    int lr = l & 15, lhi = l >> 4;
    f32x4 acc[4][4] = {};

    for (int k0 = 0; k0 < K; k0 += 32) {
        __syncthreads();
        #pragma unroll
        for (int r = 0; r < 2; r++) {
            int e = (r * 256 + tid) * 8;
            int row = e >> 5, col = e & 31;
            __builtin_amdgcn_global_load_lds(
                (const __attribute__((address_space(1))) unsigned int*)(A + (long)(m0 + row) * lda + k0 + col),
                (__attribute__((address_space(3))) unsigned int*)(&As[e]), 16, 0, 0);
            __builtin_amdgcn_global_load_lds(
                (const __attribute__((address_space(1))) unsigned int*)(Bt + (long)(n0 + row) * ldb + k0 + col),
                (__attribute__((address_space(3))) unsigned int*)(&Bs[e]), 16, 0, 0);
        }
        __syncthreads();
        bf16x8 af[4], bfr[4];
        #pragma unroll
        for (int mt = 0; mt < 4; mt++)
            af[mt] = *(const bf16x8*)&As[(wm + mt * 16 + lr) * 32 + lhi * 8];
        #pragma unroll
        for (int nt = 0; nt < 4; nt++)
            bfr[nt] = *(const bf16x8*)&Bs[(wn + nt * 16 + lr) * 32 + lhi * 8];
        #pragma unroll
        for (int mt = 0; mt < 4; mt++)
            #pragma unroll
            for (int nt = 0; nt < 4; nt++)
                acc[mt][nt] = __builtin_amdgcn_mfma_f32_16x16x32_bf16(af[mt], bfr[nt], acc[mt][nt], 0, 0, 0);
    }

    #pragma unroll
    for (int mt = 0; mt < 4; mt++) {
        #pragma unroll
        for (int i = 0; i < 4; i++) {
            int row = m0 + wm + mt * 16 + lhi * 4 + i;
            long base = coff + (long)row * ldc + n0 + wn;
            #pragma unroll
            for (int nt = 0; nt < 4; nt++) {
                float val = acc[mt][nt][i];
                int colo = nt * 16 + lr;
                if (OUTF32) Cf[base + colo] = val;
                else        Cb[base + colo] = f2bf(val);
            }
        }
    }
}

// ------------- flash attention v3b: dbuf K (counted vmcnt), V direct from L2 -------------
// P swizzle: ((row>>2)&3)<<4 — in-row (bits [5:4] of a 64B row, bijective), and the 4 rows
// written per ds_write instruction {i,4+i,8+i,12+i} map to 4 distinct 16B slots (conflict-free).
__global__ __launch_bounds__(256) void flash3_kernel(
    const short* __restrict__ qlat,  // [H][B][T][L]
    const short* __restrict__ kv,    // [B][T][L]
    const short* __restrict__ vt,    // [B][H][S][T]
    short* __restrict__ y)           // [B][T][C]
{
    __shared__ __align__(16) short Ks[2][32 * 512];   // 2 x 32 KB (double-buffered)
    __shared__ __align__(16) short Ps[4 * 16 * 32];   // 4 KB (1 KB per wave, wave-private)

    int qt = gridDim.x - 1 - blockIdx.x;              // heaviest tiles first
    int t0 = qt * 64;
    int h = blockIdx.y, b = blockIdx.z;
    int tid = threadIdx.x;
    int w = tid >> 6, l = tid & 63, lr = l & 15, lhi = l >> 4;
    int wt0 = t0 + w * 16;
    const short* qb  = qlat + ((long)(h * B_SZ + b)) * T_SEQ * L_DIM;
    const short* kvb = kv + (long)b * T_SEQ * L_DIM;
    const short* vtb = vt + ((long)(b * H_NUM + h)) * S_DIM * T_SEQ;
    short* Pw = Ps + w * 512;

    bf16x8 qf[16];
    #pragma unroll
    for (int ks = 0; ks < 16; ks++)
        qf[ks] = *(const bf16x8*)&qb[(long)(wt0 + lr) * L_DIM + ks * 32 + lhi * 8];

    f32x4 yacc[8] = {};
    float mrun[4], lrun[4];
    #pragma unroll
    for (int i = 0; i < 4; i++) { mrun[i] = -__builtin_inff(); lrun[i] = 0.f; }
    const float scale = 0.022097086912079608f;  // 1/sqrt(2048)

    int nchunk = (t0 >> 5) + 2;

    // prologue: stage chunk 0 into Ks[0] (8 x 16B per thread; src pre-swizzled, dest linear)
    #pragma unroll
    for (int r = 0; r < 8; r++) {
        int flat = r * 4096 + tid * 16;
        int row = flat >> 10, colb = flat & 1023;
        int src = (row << 10) + (colb ^ ((row & 7) << 4));
        __builtin_amdgcn_global_load_lds(
            (const __attribute__((address_space(1))) unsigned int*)((const char*)kvb + src),
            (__attribute__((address_space(3))) unsigned int*)((char*)Ks[0] + flat), 16, 0, 0);
    }

    for (int c = 0; c < nchunk; c++) {
        int cur = c & 1;
        int s0 = c * 32;
        // barrier A: all waves done reading Ks[cur^1] (prev chunk) -> safe to overwrite
        asm volatile("s_waitcnt lgkmcnt(0)" ::: "memory");
        __builtin_amdgcn_s_barrier();
        if (c + 1 < nchunk) {
            int s0n = s0 + 32;
            #pragma unroll
            for (int r = 0; r < 8; r++) {
                int flat = r * 4096 + tid * 16;
                int row = flat >> 10, colb = flat & 1023;
                int src = ((s0n + row) << 10) + (colb ^ ((row & 7) << 4));
                __builtin_amdgcn_global_load_lds(
                    (const __attribute__((address_space(1))) unsigned int*)((const char*)kvb + src),
                    (__attribute__((address_space(3))) unsigned int*)((char*)Ks[cur ^ 1] + flat), 16, 0, 0);
            }
            asm volatile("s_waitcnt vmcnt(8)" ::: "memory");  // current buf's 8 loads retired
        } else {
            asm volatile("s_waitcnt vmcnt(0)" ::: "memory");
        }
        __builtin_amdgcn_s_barrier();                         // barrier B: Ks[cur] ready

        bool active = (s0 < wt0 + 16);   // wave-uniform
        if (active) {
            // ---- hoist V fragment loads (L2-resident vt), hide latency under softmax ----
            bf16x8 vf[8];
            #pragma unroll
            for (int st = 0; st < 8; st++)
                vf[st] = *(const bf16x8*)&vtb[(long)(st * 16 + lr) * T_SEQ + s0 + lhi * 8];

            // ---- QK^T: two 16-col tiles, each as 2 independent 8-MFMA chains ----
            f32x4 sc[2];
            #pragma unroll
            for (int ct = 0; ct < 2; ct++) {
                int row = ct * 16 + lr;
                int swz = (row & 7) << 4;
                const char* kbase = (const char*)Ks[cur] + (row << 10);
                f32x4 sA = {}, sB = {};
                #pragma unroll
                for (int ks = 0; ks < 8; ks++) {
                    bf16x8 kfA = *(const bf16x8*)(kbase + ((ks * 64 + lhi * 16) ^ swz));
                    bf16x8 kfB = *(const bf16x8*)(kbase + (((ks + 8) * 64 + lhi * 16) ^ swz));
                    sA = __builtin_amdgcn_mfma_f32_16x16x32_bf16(qf[ks], kfA, sA, 0, 0, 0);
                    sB = __builtin_amdgcn_mfma_f32_16x16x32_bf16(qf[ks + 8], kfB, sB, 0, 0, 0);
                }
                sc[ct] = sA + sB;
            }
            // ---- masking + row max ----
            float p0[4], p1[4], mx[4];
            #pragma unroll
            for (int i = 0; i < 4; i++) {
                int trow = wt0 + lhi * 4 + i;
                float a0 = sc[0][i] * scale, a1 = sc[1][i] * scale;
                if (s0 + lr > trow)      a0 = -__builtin_inff();
                if (s0 + 16 + lr > trow) a1 = -__builtin_inff();
                p0[i] = a0; p1[i] = a1;
                mx[i] = fmaxf(a0, a1);
            }
            #pragma unroll
            for (int off = 1; off < 16; off <<= 1)
                #pragma unroll
                for (int i = 0; i < 4; i++)
                    mx[i] = fmaxf(mx[i], __shfl_xor(mx[i], off, 16));
            // ---- defer-rescale (T13, THR=0 -> exact): skip yacc pass when no row max grew ----
            unsigned long long grew = __ballot(mx[0] > mrun[0] || mx[1] > mrun[1] ||
                                               mx[2] > mrun[2] || mx[3] > mrun[3]);
            float lsum[4];
            if (grew) {
                float fac[4];
                #pragma unroll
                for (int i = 0; i < 4; i++) {
                    float mnew = fmaxf(mrun[i], mx[i]);
                    fac[i] = __expf(mrun[i] - mnew);
                    mrun[i] = mnew;
                }
                #pragma unroll
                for (int st = 0; st < 8; st++)
                    #pragma unroll
                    for (int i = 0; i < 4; i++)
                        yacc[st][i] *= fac[i];
                #pragma unroll
                for (int i = 0; i < 4; i++) lrun[i] *= fac[i];
            }
            #pragma unroll
            for (int i = 0; i < 4; i++) {
                p0[i] = __expf(p0[i] - mrun[i]);
                p1[i] = __expf(p1[i] - mrun[i]);
                lsum[i] = p0[i] + p1[i];
            }
            #pragma unroll
            for (int off = 1; off < 16; off <<= 1)
                #pragma unroll
                for (int i = 0; i < 4; i++)
                    lsum[i] += __shfl_xor(lsum[i], off, 16);
            #pragma unroll
            for (int i = 0; i < 4; i++) lrun[i] += lsum[i];

            // ---- write P (wave-private; swizzle ((row>>2)&3)<<4 separates the 4 rows/op) ----
            #pragma unroll
            for (int i = 0; i < 4; i++) {
                int row = lhi * 4 + i;
                int swz = ((row >> 2) & 3) << 4;
                char* pb = (char*)Pw + row * 64;
                *(short*)(pb + ((lr * 2) ^ swz))        = f2bf(p0[i]);
                *(short*)(pb + (((16 + lr) * 2) ^ swz)) = f2bf(p1[i]);
            }
            // in-wave RAW through LDS: drain writes, and fence the scheduler (rule #18)
            asm volatile("s_waitcnt lgkmcnt(0)" ::: "memory");
            __builtin_amdgcn_sched_barrier(0);
            // ---- PV: P from LDS (matching swizzle on row lr), V from regs ----
            bf16x8 pf = *(const bf16x8*)((const char*)Pw + lr * 64 +
                                         ((lhi * 16) ^ (((lr >> 2) & 3) << 4)));
            #pragma unroll
            for (int st = 0; st < 8; st++)
                yacc[st] = __builtin_amdgcn_mfma_f32_16x16x32_bf16(pf, vf[st], yacc[st], 0, 0, 0);
        }
    }

    #pragma unroll
    for (int st = 0; st < 8; st++)
        #pragma unroll
        for (int i = 0; i < 4; i++) {
            int trow = wt0 + lhi * 4 + i;
            float val = yacc[st][i] / lrun[i];
            y[((long)(b * T_SEQ + trow)) * C_DIM + h * S_DIM + st * 16 + lr] = f2bf(val);
        }
}

extern "C" void kernel_launch(void* const* d_in, const int* in_sizes, int n_in,
                              void* d_out, int out_size, void* d_ws, size_t ws_size,
                              hipStream_t stream) {
    const float* x    = (const float*)d_in[0];
    const float* wdkv = (const float*)d_in[1];
    const float* wuk  = (const float*)d_in[2];
    const float* wuv  = (const float*)d_in[3];
    const float* wq   = (const float*)d_in[4];
    const float* wo   = (const float*)d_in[5];
    float* out = (float*)d_out;

    short* ws = (short*)d_ws;
    size_t off = 0;
    short* xb    = ws + off; off += (size_t)4096 * 2048;   // x bf16 [B*T][C]   (reused as vt)
    short* wqT   = ws + off; off += (size_t)2048 * 2048;   // [C_out][C_in]
    short* wdkvT = ws + off; off += (size_t)512 * 2048;    // [L][C]
    short* wukT  = ws + off; off += (size_t)512 * 2048;    // [L][C]
    short* wuvT  = ws + off; off += (size_t)2048 * 512;    // [C][L]
    short* woT   = ws + off; off += (size_t)2048 * 2048;   // [C][C]
    short* q     = ws + off; off += (size_t)4096 * 2048;   // [B*T][C]         (reused as y)
    short* kvb   = ws + off; off += (size_t)4096 * 512;    // [B*T][L]
    short* vbuf  = ws + off; off += (size_t)4096 * 2048;   // [B*T][C]
    short* qlat  = ws + off; off += (size_t)H_NUM * B_SZ * T_SEQ * L_DIM; // [H][B][T][L]
    short* vtb  = xb;   // vt [B][H][S][T], aliases xb (dead by then)
    short* ybuf = q;    // y  [B][T][C],   aliases q  (dead by then)

    // casts / transposes
    cast_bf16_kernel<<<8192, 256, 0, stream>>>(x, xb, 2097152);
    tcast_kernel<<<dim3(2048 / 32, 2048 / 8), 256, 0, stream>>>(wq, wqT, 2048, 2048);
    tcast_kernel<<<dim3(512 / 32, 2048 / 8), 256, 0, stream>>>(wdkv, wdkvT, 2048, 512);
    tcast_kernel<<<dim3(512 / 32, 2048 / 8), 256, 0, stream>>>(wuk, wukT, 2048, 512);
    tcast_kernel<<<dim3(2048 / 32, 512 / 8), 256, 0, stream>>>(wuv, wuvT, 512, 2048);
    tcast_kernel<<<dim3(2048 / 32, 2048 / 8), 256, 0, stream>>>(wo, woT, 2048, 2048);

    // q = x @ w_q            [4096 x 2048] k=2048
    gemm_bt_kernel<0><<<dim3(16, 32, 1), 256, 0, stream>>>(xb, wqT, nullptr, q,
        4096, 2048, 2048, 2048, 2048, 2048, 0, 0, 0);
    // kv = x @ w_dkv         [4096 x 512] k=2048
    gemm_bt_kernel<0><<<dim3(4, 32, 1), 256, 0, stream>>>(xb, wdkvT, nullptr, kvb,
        4096, 512, 2048, 2048, 2048, 512, 0, 0, 0);
    // qlat[h] = q_h @ w_uk_h [4096 x 512] k=128, batched over 16 heads
    gemm_bt_kernel<0><<<dim3(4, 32, 16), 256, 0, stream>>>(q, wukT, nullptr, qlat,
        4096, 512, 128, 2048, 2048, 512, 128, 128, (long)B_SZ * T_SEQ * L_DIM);
    // v = kv @ w_uv          [4096 x 2048] k=512
    gemm_bt_kernel<0><<<dim3(16, 32, 1), 256, 0, stream>>>(kvb, wuvT, nullptr, vbuf,
        4096, 2048, 512, 512, 512, 2048, 0, 0, 0);
    // v transpose -> [B][H][S][T]
    vtrans_kernel<<<32768, 256, 0, stream>>>(vbuf, vtb);
    // flash attention v3b -> y [B][T][C]
    flash3_kernel<<<dim3(T_SEQ / 64, H_NUM, B_SZ), 256, 0, stream>>>(qlat, kvb, vtb, ybuf);
    // out = y @ w_o          [4096 x 2048] k=2048, fp32 out
    gemm_bt_kernel<1><<<dim3(16, 32, 1), 256, 0, stream>>>(ybuf, woT, out, nullptr,
        4096, 2048, 2048, 2048, 2048, 2048, 0, 0, 0);
}